// Round 1
// baseline (3097.463 us; speedup 1.0000x reference)
//
#include <hip/hip_runtime.h>
#include <hip/hip_bf16.h>
#include <math.h>

#define NF 128          // feature width (both layers): 2 heads x 64
#define HEADS 2
#define HD 64

// ---------------------------------------------------------------------------
// float atomic max via signed-max / unsigned-min bit trick
// ---------------------------------------------------------------------------
__device__ inline void atomicMaxFloat(float* addr, float v) {
    if (v >= 0.0f) {
        atomicMax((int*)addr, __float_as_int(v));
    } else {
        atomicMin((unsigned int*)addr, (unsigned int)__float_as_int(v));
    }
}

__device__ inline float leaky02(float v) {
    return v >= 0.0f ? v : 0.2f * v;
}

// ---------------------------------------------------------------------------
// Fused GEMM + attention logits.
// H[n][c] = sum_f X[n][f] * W[f][c]        (c = head*64 + d)
// el[n][h] = sum_d H[n][h][d] * al[h][d];  er likewise.
// Block: 256 threads, 16 rows x 128 cols, each thread 8 rows.
// Wave = 64 lanes = one head's 64 d-columns for 8 rows -> shuffle reduce.
// ---------------------------------------------------------------------------
__global__ __launch_bounds__(256) void gemm_attn(
    const float* __restrict__ X, const float* __restrict__ W,
    const float* __restrict__ al, const float* __restrict__ ar,
    float* __restrict__ H, float* __restrict__ el, float* __restrict__ er,
    int n)
{
    __shared__ float Xs[16][NF];
    const int t   = threadIdx.x;
    const int tx  = t & 127;     // output column
    const int ty  = t >> 7;      // 0..1
    const int row0 = blockIdx.x * 16;

    for (int i = t; i < 16 * NF; i += 256) {
        int r = i >> 7, c = i & 127;
        int gr = row0 + r;
        Xs[r][c] = (gr < n) ? X[gr * NF + c] : 0.0f;
    }
    __syncthreads();

    float acc[8];
#pragma unroll
    for (int i = 0; i < 8; i++) acc[i] = 0.0f;

    for (int k = 0; k < NF; k++) {
        float wv = W[k * NF + tx];
#pragma unroll
        for (int i = 0; i < 8; i++) acc[i] += Xs[ty + 2 * i][k] * wv;
    }

    const float av = al[tx];
    const float rv = ar[tx];
    const int head = tx >> 6;
    const int dlane = tx & 63;

#pragma unroll
    for (int i = 0; i < 8; i++) {
        int gr = row0 + ty + 2 * i;
        if (gr < n) H[gr * NF + tx] = acc[i];
        float s1 = acc[i] * av;
        float s2 = acc[i] * rv;
#pragma unroll
        for (int off = 32; off; off >>= 1) {
            s1 += __shfl_xor(s1, off, 64);
            s2 += __shfl_xor(s2, off, 64);
        }
        if (dlane == 0 && gr < n) {
            el[gr * 2 + head] = s1;
            er[gr * 2 + head] = s2;
        }
    }
}

// ---------------------------------------------------------------------------
__global__ __launch_bounds__(256) void init_md(float* __restrict__ m,
                                               float* __restrict__ denom, int n2)
{
    int i = blockIdx.x * 256 + threadIdx.x;
    if (i < n2) { m[i] = -INFINITY; denom[i] = 0.0f; }
}

__global__ __launch_bounds__(256) void init_acc(float* __restrict__ acc,
                                                const float* __restrict__ b,
                                                int total)  // N*128, b: [3][128]
{
    int i = blockIdx.x * 256 + threadIdx.x;
    if (i < total) {
        int c = i & 127;
        acc[i] = b[c] + b[128 + c] + b[256 + c];
    }
}

// ---------------------------------------------------------------------------
__global__ __launch_bounds__(256) void edge_max(
    const int* __restrict__ src, const int* __restrict__ dst,
    const float* __restrict__ el, const float* __restrict__ er,
    float* __restrict__ m, int E)
{
    int i = blockIdx.x * 256 + threadIdx.x;
    if (i >= E * 2) return;
    int e = i >> 1, h = i & 1;
    int s = src[e], d = dst[e];
    float v = leaky02(el[s * 2 + h] + er[d * 2 + h]) + 0.0f;  // canonicalize -0
    atomicMaxFloat(&m[d * 2 + h], v);
}

__global__ __launch_bounds__(256) void edge_exp(
    const int* __restrict__ src, const int* __restrict__ dst,
    const float* __restrict__ el, const float* __restrict__ er,
    const float* __restrict__ m, float* __restrict__ ex,
    float* __restrict__ denom, int E)
{
    int i = blockIdx.x * 256 + threadIdx.x;
    if (i >= E * 2) return;
    int e = i >> 1, h = i & 1;
    int s = src[e], d = dst[e];
    float v = leaky02(el[s * 2 + h] + er[d * 2 + h]);
    float xv = expf(v - m[d * 2 + h]);
    ex[i] = xv;
    atomicAdd(&denom[d * 2 + h], xv);
}

// one wave per edge; lane = d within head, handles both heads
__global__ __launch_bounds__(256) void edge_scatter(
    const int* __restrict__ src, const int* __restrict__ dst,
    const float* __restrict__ ex, const float* __restrict__ denom,
    const float* __restrict__ H, float* __restrict__ acc, int E)
{
    int wid = (int)((blockIdx.x * 256 + threadIdx.x) >> 6);
    int lane = threadIdx.x & 63;
    if (wid >= E) return;
    int s = src[wid], d = dst[wid];
    float a0 = ex[wid * 2]     / denom[d * 2];
    float a1 = ex[wid * 2 + 1] / denom[d * 2 + 1];
    float h0 = H[s * NF + lane];
    float h1 = H[s * NF + 64 + lane];
    atomicAdd(&acc[d * NF + lane],      a0 * h0);
    atomicAdd(&acc[d * NF + 64 + lane], a1 * h1);
}

// ---------------------------------------------------------------------------
__global__ __launch_bounds__(256) void relu_inplace(float* __restrict__ a, int total)
{
    int i = blockIdx.x * 256 + threadIdx.x;
    if (i < total) { float v = a[i]; a[i] = v > 0.0f ? v : 0.0f; }
}

__global__ __launch_bounds__(256) void head_mean(const float* __restrict__ a,
                                                 float* __restrict__ out, int n)
{
    int i = blockIdx.x * 256 + threadIdx.x;
    if (i >= n * 64) return;
    int node = i >> 6, d = i & 63;
    out[i] = 0.5f * (a[node * NF + d] + a[node * NF + 64 + d]);
}

// ---------------------------------------------------------------------------
extern "C" void kernel_launch(void* const* d_in, const int* in_sizes, int n_in,
                              void* d_out, int out_size, void* d_ws, size_t ws_size,
                              hipStream_t stream)
{
    const float* x   = (const float*)d_in[0];
    const int*   src = (const int*)  d_in[1];
    const int*   dst = (const int*)  d_in[2];
    const float* W1  = (const float*)d_in[3];
    const float* al1 = (const float*)d_in[4];
    const float* ar1 = (const float*)d_in[5];
    const float* b1  = (const float*)d_in[6];
    const float* W2  = (const float*)d_in[7];
    const float* al2 = (const float*)d_in[8];
    const float* ar2 = (const float*)d_in[9];
    const float* b2  = (const float*)d_in[10];

    const int N = in_sizes[0] / NF;          // 100000
    const int R = 3;
    const int E = in_sizes[1] / R;           // 800000

    float* ws    = (float*)d_ws;
    float* Hbuf  = ws;
    float* accA  = Hbuf + (size_t)N * NF;
    float* accB  = accA + (size_t)N * NF;
    float* el    = accB + (size_t)N * NF;
    float* er    = el + (size_t)N * 2;
    float* mbuf  = er + (size_t)N * 2;
    float* denom = mbuf + (size_t)N * 2;
    float* exbuf = denom + (size_t)N * 2;

    const int nodeBlocks  = (N * NF + 255) / 256;        // N*128 elementwise
    const int gemmBlocks  = (N + 15) / 16;
    const int edgeBlocks  = (E * 2 + 255) / 256;
    const int scatBlocks  = (E + 3) / 4;                 // 4 waves per block
    const int mdBlocks    = (N * 2 + 255) / 256;

    // ---------------- layer 1 ----------------
    init_acc<<<nodeBlocks, 256, 0, stream>>>(accA, b1, N * NF);
    for (int r = 0; r < R; r++) {
        const int* sr = src + (size_t)r * E;
        const int* dr = dst + (size_t)r * E;
        gemm_attn<<<gemmBlocks, 256, 0, stream>>>(
            x, W1 + (size_t)r * NF * NF, al1 + r * NF, ar1 + r * NF,
            Hbuf, el, er, N);
        init_md<<<mdBlocks, 256, 0, stream>>>(mbuf, denom, N * 2);
        edge_max<<<edgeBlocks, 256, 0, stream>>>(sr, dr, el, er, mbuf, E);
        edge_exp<<<edgeBlocks, 256, 0, stream>>>(sr, dr, el, er, mbuf, exbuf, denom, E);
        edge_scatter<<<scatBlocks, 256, 0, stream>>>(sr, dr, exbuf, denom, Hbuf, accA, E);
    }
    relu_inplace<<<nodeBlocks, 256, 0, stream>>>(accA, N * NF);

    // ---------------- layer 2 ----------------
    init_acc<<<nodeBlocks, 256, 0, stream>>>(accB, b2, N * NF);
    for (int r = 0; r < R; r++) {
        const int* sr = src + (size_t)r * E;
        const int* dr = dst + (size_t)r * E;
        gemm_attn<<<gemmBlocks, 256, 0, stream>>>(
            accA, W2 + (size_t)r * NF * NF, al2 + r * NF, ar2 + r * NF,
            Hbuf, el, er, N);
        init_md<<<mdBlocks, 256, 0, stream>>>(mbuf, denom, N * 2);
        edge_max<<<edgeBlocks, 256, 0, stream>>>(sr, dr, el, er, mbuf, E);
        edge_exp<<<edgeBlocks, 256, 0, stream>>>(sr, dr, el, er, mbuf, exbuf, denom, E);
        edge_scatter<<<scatBlocks, 256, 0, stream>>>(sr, dr, exbuf, denom, Hbuf, accB, E);
    }

    head_mean<<<(N * 64 + 255) / 256, 256, 0, stream>>>(accB, (float*)d_out, N);
}

// Round 2
// 1916.150 us; speedup vs baseline: 1.6165x; 1.6165x over previous
//
#include <hip/hip_runtime.h>
#include <hip/hip_bf16.h>
#include <math.h>

#define NF 128          // feature width (both layers): 2 heads x 64
#define HEADS 2
#define HD 64

__device__ inline float leaky02(float v) {
    return v >= 0.0f ? v : 0.2f * v;
}

// ---------------------------------------------------------------------------
// Fused GEMM + attention logits.
// H[n][c] = sum_f X[n][f] * W[f][c]        (c = head*64 + d)
// el[n][h] = sum_d H[n][h][d] * al[h][d];  er likewise.
// Block: 256 threads, 16 rows x 128 cols, each thread 8 rows.
// ---------------------------------------------------------------------------
__global__ __launch_bounds__(256) void gemm_attn(
    const float* __restrict__ X, const float* __restrict__ W,
    const float* __restrict__ al, const float* __restrict__ ar,
    float* __restrict__ H, float* __restrict__ el, float* __restrict__ er,
    int n)
{
    __shared__ float Xs[16][NF];
    const int t   = threadIdx.x;
    const int tx  = t & 127;     // output column
    const int ty  = t >> 7;      // 0..1
    const int row0 = blockIdx.x * 16;

    for (int i = t; i < 16 * NF; i += 256) {
        int r = i >> 7, c = i & 127;
        int gr = row0 + r;
        Xs[r][c] = (gr < n) ? X[gr * NF + c] : 0.0f;
    }
    __syncthreads();

    float acc[8];
#pragma unroll
    for (int i = 0; i < 8; i++) acc[i] = 0.0f;

    for (int k = 0; k < NF; k++) {
        float wv = W[k * NF + tx];
#pragma unroll
        for (int i = 0; i < 8; i++) acc[i] += Xs[ty + 2 * i][k] * wv;
    }

    const float av = al[tx];
    const float rv = ar[tx];
    const int head = tx >> 6;
    const int dlane = tx & 63;

#pragma unroll
    for (int i = 0; i < 8; i++) {
        int gr = row0 + ty + 2 * i;
        if (gr < n) H[gr * NF + tx] = acc[i];
        float s1 = acc[i] * av;
        float s2 = acc[i] * rv;
#pragma unroll
        for (int off = 32; off; off >>= 1) {
            s1 += __shfl_xor(s1, off, 64);
            s2 += __shfl_xor(s2, off, 64);
        }
        if (dlane == 0 && gr < n) {
            el[gr * 2 + head] = s1;
            er[gr * 2 + head] = s2;
        }
    }
}

// ---------------------------------------------------------------------------
// CSR build: histogram -> scan -> place
// ---------------------------------------------------------------------------
__global__ __launch_bounds__(256) void hist_kernel(
    const int* __restrict__ dst, int* __restrict__ deg, int E)
{
    int i = blockIdx.x * 256 + threadIdx.x;
    if (i < E) atomicAdd(&deg[dst[i]], 1);
}

// inclusive scan of 256-chunks; partial per element, block total to bsum
__global__ __launch_bounds__(256) void scan1(
    const int* __restrict__ deg, int* __restrict__ partial,
    int* __restrict__ bsum, int n)
{
    __shared__ int s[256];
    int i = blockIdx.x * 256 + threadIdx.x;
    int t = threadIdx.x;
    int v = (i < n) ? deg[i] : 0;
    s[t] = v;
    __syncthreads();
    for (int off = 1; off < 256; off <<= 1) {
        int x = (t >= off) ? s[t - off] : 0;
        __syncthreads();
        s[t] += x;
        __syncthreads();
    }
    if (i < n) partial[i] = s[t];
    if (t == 255) bsum[blockIdx.x] = s[255];
}

// exclusive scan of block sums (nb <= 512), single block of 512
__global__ __launch_bounds__(512) void scan2(int* __restrict__ bsum, int nb)
{
    __shared__ int s[512];
    int t = threadIdx.x;
    int v = (t < nb) ? bsum[t] : 0;
    s[t] = v;
    __syncthreads();
    for (int off = 1; off < 512; off <<= 1) {
        int x = (t >= off) ? s[t - off] : 0;
        __syncthreads();
        s[t] += x;
        __syncthreads();
    }
    if (t < nb) bsum[t] = s[t] - v;   // exclusive
}

// rowptr[i+1] = partial[i] + bsum[block]; rowptr[0] = 0
__global__ __launch_bounds__(256) void scan3(
    const int* __restrict__ partial, const int* __restrict__ bsum,
    int* __restrict__ rowptr, int n)
{
    int i = blockIdx.x * 256 + threadIdx.x;
    if (i < n) rowptr[i + 1] = partial[i] + bsum[blockIdx.x];
    if (i == 0) rowptr[0] = 0;
}

__global__ __launch_bounds__(256) void place_kernel(
    const int* __restrict__ src, const int* __restrict__ dst,
    const int* __restrict__ rowptr, int* __restrict__ cnt,
    int* __restrict__ csr_src, int E)
{
    int e = blockIdx.x * 256 + threadIdx.x;
    if (e >= E) return;
    int d = dst[e];
    int pos = rowptr[d] + atomicAdd(&cnt[d], 1);
    csr_src[pos] = src[e];
}

// ---------------------------------------------------------------------------
__global__ __launch_bounds__(256) void init_acc(float* __restrict__ acc,
                                                const float* __restrict__ b,
                                                int total)  // N*128, b: [3][128]
{
    int i = blockIdx.x * 256 + threadIdx.x;
    if (i < total) {
        int c = i & 127;
        acc[i] = b[c] + b[128 + c] + b[256 + c];
    }
}

// ---------------------------------------------------------------------------
// Per-destination-node softmax + gather-aggregate. One wave per node.
// lane = d within head; handles head0 at [lane], head1 at [64+lane].
// Pass 1: online max+denom over in-edges (scalar, redundant across lanes).
// Pass 2: gather H[src] rows once, weighted accumulate in registers.
// ---------------------------------------------------------------------------
__global__ __launch_bounds__(256) void aggregate(
    const int* __restrict__ rowptr, const int* __restrict__ csr_src,
    const float* __restrict__ el, const float* __restrict__ er,
    const float* __restrict__ H, float* __restrict__ acc, int n)
{
    int node = (int)((blockIdx.x * 256 + threadIdx.x) >> 6);
    int lane = threadIdx.x & 63;
    if (node >= n) return;
    int beg = rowptr[node], end = rowptr[node + 1];
    if (beg == end) return;

    const float e0r = er[node * 2];
    const float e1r = er[node * 2 + 1];

    float m0 = -INFINITY, m1 = -INFINITY, d0 = 0.0f, d1 = 0.0f;
    for (int i = beg; i < end; i++) {
        int s = csr_src[i];
        float v0 = leaky02(el[s * 2]     + e0r);
        float v1 = leaky02(el[s * 2 + 1] + e1r);
        float n0 = fmaxf(m0, v0), n1 = fmaxf(m1, v1);
        d0 = d0 * __expf(m0 - n0) + __expf(v0 - n0);
        d1 = d1 * __expf(m1 - n1) + __expf(v1 - n1);
        m0 = n0; m1 = n1;
    }
    const float inv0 = 1.0f / d0;
    const float inv1 = 1.0f / d1;

    float a0 = 0.0f, a1 = 0.0f;
    for (int i = beg; i < end; i++) {
        int s = csr_src[i];
        float v0 = leaky02(el[s * 2]     + e0r);
        float v1 = leaky02(el[s * 2 + 1] + e1r);
        float w0 = __expf(v0 - m0) * inv0;
        float w1 = __expf(v1 - m1) * inv1;
        a0 += w0 * H[s * NF + lane];
        a1 += w1 * H[s * NF + 64 + lane];
    }
    acc[node * NF + lane]      += a0;
    acc[node * NF + 64 + lane] += a1;
}

// ---------------------------------------------------------------------------
__global__ __launch_bounds__(256) void relu_inplace(float* __restrict__ a, int total)
{
    int i = blockIdx.x * 256 + threadIdx.x;
    if (i < total) { float v = a[i]; a[i] = v > 0.0f ? v : 0.0f; }
}

__global__ __launch_bounds__(256) void head_mean(const float* __restrict__ a,
                                                 float* __restrict__ out, int n)
{
    int i = blockIdx.x * 256 + threadIdx.x;
    if (i >= n * 64) return;
    int node = i >> 6, d = i & 63;
    out[i] = 0.5f * (a[node * NF + d] + a[node * NF + 64 + d]);
}

// ---------------------------------------------------------------------------
extern "C" void kernel_launch(void* const* d_in, const int* in_sizes, int n_in,
                              void* d_out, int out_size, void* d_ws, size_t ws_size,
                              hipStream_t stream)
{
    const float* x   = (const float*)d_in[0];
    const int*   src = (const int*)  d_in[1];
    const int*   dst = (const int*)  d_in[2];
    const float* W1  = (const float*)d_in[3];
    const float* al1 = (const float*)d_in[4];
    const float* ar1 = (const float*)d_in[5];
    const float* b1  = (const float*)d_in[6];
    const float* W2  = (const float*)d_in[7];
    const float* al2 = (const float*)d_in[8];
    const float* ar2 = (const float*)d_in[9];
    const float* b2  = (const float*)d_in[10];

    const int N = in_sizes[0] / NF;          // 100000
    const int R = 3;
    const int E = in_sizes[1] / R;           // 800000

    float* ws    = (float*)d_ws;
    float* Hbuf  = ws;                               // N*128
    float* accA  = Hbuf + (size_t)N * NF;            // N*128
    float* accB  = accA + (size_t)N * NF;            // N*128
    float* el    = accB + (size_t)N * NF;            // N*2
    float* er    = el + (size_t)N * 2;               // N*2
    int*   rowptr  = (int*)(er + (size_t)N * 2);     // 3*(N+1)
    int*   csr_src = rowptr + 3 * (N + 1);           // 3*E
    // CSR-build scratch aliased onto accB (only used before layer 2 init)
    int*   deg     = (int*)accB;                     // N
    int*   partial = deg + N;                        // N
    int*   cnt     = partial + N;                    // N
    int*   bsum    = cnt + N;                        // <=512

    const int nodeBlocks  = (N * NF + 255) / 256;
    const int gemmBlocks  = (N + 15) / 16;
    const int edgeBlocks  = (E + 255) / 256;
    const int aggBlocks   = (N + 3) / 4;             // one wave per node
    const int scanBlocks  = (N + 255) / 256;

    // ---------------- build CSR for all 3 relations (graph shared by layers)
    for (int r = 0; r < R; r++) {
        const int* dr = dst + (size_t)r * E;
        int* rp = rowptr + r * (N + 1);
        int* cs = csr_src + (size_t)r * E;
        hipMemsetAsync(deg, 0, (size_t)N * 4, stream);
        hipMemsetAsync(cnt, 0, (size_t)N * 4, stream);
        hist_kernel<<<edgeBlocks, 256, 0, stream>>>(dr, deg, E);
        scan1<<<scanBlocks, 256, 0, stream>>>(deg, partial, bsum, N);
        scan2<<<1, 512, 0, stream>>>(bsum, scanBlocks);
        scan3<<<scanBlocks, 256, 0, stream>>>(partial, bsum, rp, N);
        place_kernel<<<edgeBlocks, 256, 0, stream>>>(
            src + (size_t)r * E, dr, rp, cnt, cs, E);
    }

    // ---------------- layer 1 ----------------
    init_acc<<<nodeBlocks, 256, 0, stream>>>(accA, b1, N * NF);
    for (int r = 0; r < R; r++) {
        gemm_attn<<<gemmBlocks, 256, 0, stream>>>(
            x, W1 + (size_t)r * NF * NF, al1 + r * NF, ar1 + r * NF,
            Hbuf, el, er, N);
        aggregate<<<aggBlocks, 256, 0, stream>>>(
            rowptr + r * (N + 1), csr_src + (size_t)r * E, el, er, Hbuf, accA, N);
    }
    relu_inplace<<<nodeBlocks, 256, 0, stream>>>(accA, N * NF);

    // ---------------- layer 2 ----------------
    init_acc<<<nodeBlocks, 256, 0, stream>>>(accB, b2, N * NF);
    for (int r = 0; r < R; r++) {
        gemm_attn<<<gemmBlocks, 256, 0, stream>>>(
            accA, W2 + (size_t)r * NF * NF, al2 + r * NF, ar2 + r * NF,
            Hbuf, el, er, N);
        aggregate<<<aggBlocks, 256, 0, stream>>>(
            rowptr + r * (N + 1), csr_src + (size_t)r * E, el, er, Hbuf, accB, N);
    }

    head_mean<<<(N * 64 + 255) / 256, 256, 0, stream>>>(accB, (float*)d_out, N);
}

// Round 3
// 1357.797 us; speedup vs baseline: 2.2812x; 1.4112x over previous
//
#include <hip/hip_runtime.h>
#include <hip/hip_bf16.h>
#include <math.h>

#define NF 128          // feature width (both layers): 2 heads x 64
#define HEADS 2
#define HD 64

__device__ inline float leaky02(float v) {
    return v >= 0.0f ? v : 0.2f * v;
}

// ---------------------------------------------------------------------------
// Fused GEMM + attention logits.
// H[n][c] = sum_f X[n][f] * W[f][c]        (c = head*64 + d)
// el[n][h] = sum_d H[n][h][d] * al[h][d];  er likewise.
// Block: 256 threads, 16 rows x 128 cols, each thread 8 rows.
// ---------------------------------------------------------------------------
__global__ __launch_bounds__(256) void gemm_attn(
    const float* __restrict__ X, const float* __restrict__ W,
    const float* __restrict__ al, const float* __restrict__ ar,
    float* __restrict__ H, float* __restrict__ el, float* __restrict__ er,
    int n)
{
    __shared__ float Xs[16][NF];
    const int t   = threadIdx.x;
    const int tx  = t & 127;     // output column
    const int ty  = t >> 7;      // 0..1
    const int row0 = blockIdx.x * 16;

    for (int i = t; i < 16 * NF; i += 256) {
        int r = i >> 7, c = i & 127;
        int gr = row0 + r;
        Xs[r][c] = (gr < n) ? X[gr * NF + c] : 0.0f;
    }
    __syncthreads();

    float acc[8];
#pragma unroll
    for (int i = 0; i < 8; i++) acc[i] = 0.0f;

    for (int k = 0; k < NF; k++) {
        float wv = W[k * NF + tx];
#pragma unroll
        for (int i = 0; i < 8; i++) acc[i] += Xs[ty + 2 * i][k] * wv;
    }

    const float av = al[tx];
    const float rv = ar[tx];
    const int head = tx >> 6;
    const int dlane = tx & 63;

#pragma unroll
    for (int i = 0; i < 8; i++) {
        int gr = row0 + ty + 2 * i;
        if (gr < n) H[gr * NF + tx] = acc[i];
        float s1 = acc[i] * av;
        float s2 = acc[i] * rv;
#pragma unroll
        for (int off = 32; off; off >>= 1) {
            s1 += __shfl_xor(s1, off, 64);
            s2 += __shfl_xor(s2, off, 64);
        }
        if (dlane == 0 && gr < n) {
            el[gr * 2 + head] = s1;
            er[gr * 2 + head] = s2;
        }
    }
}

// ---------------------------------------------------------------------------
// CSR build: histogram -> scan -> place
// ---------------------------------------------------------------------------
__global__ __launch_bounds__(256) void hist_kernel(
    const int* __restrict__ dst, int* __restrict__ deg, int E)
{
    int i = blockIdx.x * 256 + threadIdx.x;
    if (i < E) atomicAdd(&deg[dst[i]], 1);
}

// inclusive scan of 256-chunks; partial per element, block total to bsum
__global__ __launch_bounds__(256) void scan1(
    const int* __restrict__ deg, int* __restrict__ partial,
    int* __restrict__ bsum, int n)
{
    __shared__ int s[256];
    int i = blockIdx.x * 256 + threadIdx.x;
    int t = threadIdx.x;
    int v = (i < n) ? deg[i] : 0;
    s[t] = v;
    __syncthreads();
    for (int off = 1; off < 256; off <<= 1) {
        int x = (t >= off) ? s[t - off] : 0;
        __syncthreads();
        s[t] += x;
        __syncthreads();
    }
    if (i < n) partial[i] = s[t];
    if (t == 255) bsum[blockIdx.x] = s[255];
}

// exclusive scan of block sums (nb <= 512), single block of 512
__global__ __launch_bounds__(512) void scan2(int* __restrict__ bsum, int nb)
{
    __shared__ int s[512];
    int t = threadIdx.x;
    int v = (t < nb) ? bsum[t] : 0;
    s[t] = v;
    __syncthreads();
    for (int off = 1; off < 512; off <<= 1) {
        int x = (t >= off) ? s[t - off] : 0;
        __syncthreads();
        s[t] += x;
        __syncthreads();
    }
    if (t < nb) bsum[t] = s[t] - v;   // exclusive
}

// rowptr[i+1] = partial[i] + bsum[block]; rowptr[0] = 0
__global__ __launch_bounds__(256) void scan3(
    const int* __restrict__ partial, const int* __restrict__ bsum,
    int* __restrict__ rowptr, int n)
{
    int i = blockIdx.x * 256 + threadIdx.x;
    if (i < n) rowptr[i + 1] = partial[i] + bsum[blockIdx.x];
    if (i == 0) rowptr[0] = 0;
}

__global__ __launch_bounds__(256) void place_kernel(
    const int* __restrict__ src, const int* __restrict__ dst,
    const int* __restrict__ rowptr, int* __restrict__ cnt,
    int* __restrict__ csr_src, int E)
{
    int e = blockIdx.x * 256 + threadIdx.x;
    if (e >= E) return;
    int d = dst[e];
    int pos = rowptr[d] + atomicAdd(&cnt[d], 1);
    csr_src[pos] = src[e];
}

// ---------------------------------------------------------------------------
__global__ __launch_bounds__(256) void init_acc(float* __restrict__ acc,
                                                const float* __restrict__ b,
                                                int total)  // N*128, b: [3][128]
{
    int i = blockIdx.x * 256 + threadIdx.x;
    if (i < total) {
        int c = i & 127;
        acc[i] = b[c] + b[128 + c] + b[256 + c];
    }
}

// ---------------------------------------------------------------------------
// Per-destination-node softmax + gather-aggregate. One wave per node.
// Lane-parallel softmax: lane = edge within chunk of 64. Wave shuffle
// reduces give exact segment max / sum (matches reference semantics).
// Gather loop: broadcast (src, w0, w1) from lane j via 3 shuffles, all 64
// lanes do the coalesced 512B row gather + FMA.
// ---------------------------------------------------------------------------
__global__ __launch_bounds__(256) void aggregate(
    const int* __restrict__ rowptr, const int* __restrict__ csr_src,
    const float* __restrict__ el, const float* __restrict__ er,
    const float* __restrict__ H, float* __restrict__ acc, int n)
{
    int node = (int)((blockIdx.x * 256 + threadIdx.x) >> 6);
    int lane = threadIdx.x & 63;
    if (node >= n) return;
    int beg = rowptr[node], end = rowptr[node + 1];
    int deg = end - beg;
    if (deg == 0) return;

    const float e0r = er[node * 2];
    const float e1r = er[node * 2 + 1];

    float a0 = 0.0f, a1 = 0.0f;

    if (deg <= 64) {
        // ---- single-chunk fast path (covers ~all nodes at mean degree 8)
        int s = 0;
        float v0 = -INFINITY, v1 = -INFINITY;
        if (lane < deg) {
            s = csr_src[beg + lane];
            float2 e = *(const float2*)(el + (size_t)s * 2);
            v0 = leaky02(e.x + e0r);
            v1 = leaky02(e.y + e1r);
        }
        float M0 = v0, M1 = v1;
#pragma unroll
        for (int off = 32; off; off >>= 1) {
            M0 = fmaxf(M0, __shfl_xor(M0, off, 64));
            M1 = fmaxf(M1, __shfl_xor(M1, off, 64));
        }
        float x0 = (lane < deg) ? __expf(v0 - M0) : 0.0f;
        float x1 = (lane < deg) ? __expf(v1 - M1) : 0.0f;
        float S0 = x0, S1 = x1;
#pragma unroll
        for (int off = 32; off; off >>= 1) {
            S0 += __shfl_xor(S0, off, 64);
            S1 += __shfl_xor(S1, off, 64);
        }
        float w0 = x0 / S0;
        float w1 = x1 / S1;

        for (int j = 0; j < deg; j++) {
            int ss    = __shfl(s, j, 64);
            float ww0 = __shfl(w0, j, 64);
            float ww1 = __shfl(w1, j, 64);
            const float* hp = H + (size_t)ss * NF;
            a0 += ww0 * hp[lane];
            a1 += ww1 * hp[64 + lane];
        }
    } else {
        // ---- general chunked path (deg > 64, rare)
        float m0 = -INFINITY, m1 = -INFINITY, d0 = 0.0f, d1 = 0.0f;
        for (int c0 = beg; c0 < end; c0 += 64) {
            int i = c0 + lane;
            float v0 = -INFINITY, v1 = -INFINITY;
            if (i < end) {
                int s = csr_src[i];
                float2 e = *(const float2*)(el + (size_t)s * 2);
                v0 = leaky02(e.x + e0r);
                v1 = leaky02(e.y + e1r);
            }
            float M0 = v0, M1 = v1;
#pragma unroll
            for (int off = 32; off; off >>= 1) {
                M0 = fmaxf(M0, __shfl_xor(M0, off, 64));
                M1 = fmaxf(M1, __shfl_xor(M1, off, 64));
            }
            float x0 = (i < end) ? __expf(v0 - M0) : 0.0f;
            float x1 = (i < end) ? __expf(v1 - M1) : 0.0f;
            float S0 = x0, S1 = x1;
#pragma unroll
            for (int off = 32; off; off >>= 1) {
                S0 += __shfl_xor(S0, off, 64);
                S1 += __shfl_xor(S1, off, 64);
            }
            float nm0 = fmaxf(m0, M0), nm1 = fmaxf(m1, M1);
            d0 = d0 * __expf(m0 - nm0) + S0 * __expf(M0 - nm0);
            d1 = d1 * __expf(m1 - nm1) + S1 * __expf(M1 - nm1);
            m0 = nm0; m1 = nm1;
        }
        float inv0 = 1.0f / d0, inv1 = 1.0f / d1;
        for (int c0 = beg; c0 < end; c0 += 64) {
            int i = c0 + lane;
            int cn = min(64, end - c0);
            int s = 0; float w0 = 0.0f, w1 = 0.0f;
            if (i < end) {
                s = csr_src[i];
                float2 e = *(const float2*)(el + (size_t)s * 2);
                w0 = __expf(leaky02(e.x + e0r) - m0) * inv0;
                w1 = __expf(leaky02(e.y + e1r) - m1) * inv1;
            }
            for (int j = 0; j < cn; j++) {
                int ss    = __shfl(s, j, 64);
                float ww0 = __shfl(w0, j, 64);
                float ww1 = __shfl(w1, j, 64);
                const float* hp = H + (size_t)ss * NF;
                a0 += ww0 * hp[lane];
                a1 += ww1 * hp[64 + lane];
            }
        }
    }
    acc[node * NF + lane]      += a0;
    acc[node * NF + 64 + lane] += a1;
}

// ---------------------------------------------------------------------------
__global__ __launch_bounds__(256) void relu_inplace(float* __restrict__ a, int total)
{
    int i = blockIdx.x * 256 + threadIdx.x;
    if (i < total) { float v = a[i]; a[i] = v > 0.0f ? v : 0.0f; }
}

__global__ __launch_bounds__(256) void head_mean(const float* __restrict__ a,
                                                 float* __restrict__ out, int n)
{
    int i = blockIdx.x * 256 + threadIdx.x;
    if (i >= n * 64) return;
    int node = i >> 6, d = i & 63;
    out[i] = 0.5f * (a[node * NF + d] + a[node * NF + 64 + d]);
}

// ---------------------------------------------------------------------------
extern "C" void kernel_launch(void* const* d_in, const int* in_sizes, int n_in,
                              void* d_out, int out_size, void* d_ws, size_t ws_size,
                              hipStream_t stream)
{
    const float* x   = (const float*)d_in[0];
    const int*   src = (const int*)  d_in[1];
    const int*   dst = (const int*)  d_in[2];
    const float* W1  = (const float*)d_in[3];
    const float* al1 = (const float*)d_in[4];
    const float* ar1 = (const float*)d_in[5];
    const float* b1  = (const float*)d_in[6];
    const float* W2  = (const float*)d_in[7];
    const float* al2 = (const float*)d_in[8];
    const float* ar2 = (const float*)d_in[9];
    const float* b2  = (const float*)d_in[10];

    const int N = in_sizes[0] / NF;          // 100000
    const int R = 3;
    const int E = in_sizes[1] / R;           // 800000

    float* ws    = (float*)d_ws;
    float* Hbuf  = ws;                               // N*128
    float* accA  = Hbuf + (size_t)N * NF;            // N*128
    float* accB  = accA + (size_t)N * NF;            // N*128
    float* el    = accB + (size_t)N * NF;            // N*2
    float* er    = el + (size_t)N * 2;               // N*2
    int*   rowptr  = (int*)(er + (size_t)N * 2);     // 3*(N+1)
    int*   csr_src = rowptr + 3 * (N + 1);           // 3*E
    // CSR-build scratch aliased onto accB (only used before layer 2 init)
    int*   deg     = (int*)accB;                     // N
    int*   partial = deg + N;                        // N
    int*   cnt     = partial + N;                    // N
    int*   bsum    = cnt + N;                        // <=512

    const int nodeBlocks  = (N * NF + 255) / 256;
    const int gemmBlocks  = (N + 15) / 16;
    const int edgeBlocks  = (E + 255) / 256;
    const int aggBlocks   = (N + 3) / 4;             // one wave per node
    const int scanBlocks  = (N + 255) / 256;

    // ---------------- build CSR for all 3 relations (graph shared by layers)
    for (int r = 0; r < R; r++) {
        const int* dr = dst + (size_t)r * E;
        int* rp = rowptr + r * (N + 1);
        int* cs = csr_src + (size_t)r * E;
        hipMemsetAsync(deg, 0, (size_t)N * 4, stream);
        hipMemsetAsync(cnt, 0, (size_t)N * 4, stream);
        hist_kernel<<<edgeBlocks, 256, 0, stream>>>(dr, deg, E);
        scan1<<<scanBlocks, 256, 0, stream>>>(deg, partial, bsum, N);
        scan2<<<1, 512, 0, stream>>>(bsum, scanBlocks);
        scan3<<<scanBlocks, 256, 0, stream>>>(partial, bsum, rp, N);
        place_kernel<<<edgeBlocks, 256, 0, stream>>>(
            src + (size_t)r * E, dr, rp, cnt, cs, E);
    }

    // ---------------- layer 1 ----------------
    init_acc<<<nodeBlocks, 256, 0, stream>>>(accA, b1, N * NF);
    for (int r = 0; r < R; r++) {
        gemm_attn<<<gemmBlocks, 256, 0, stream>>>(
            x, W1 + (size_t)r * NF * NF, al1 + r * NF, ar1 + r * NF,
            Hbuf, el, er, N);
        aggregate<<<aggBlocks, 256, 0, stream>>>(
            rowptr + r * (N + 1), csr_src + (size_t)r * E, el, er, Hbuf, accA, N);
    }
    relu_inplace<<<nodeBlocks, 256, 0, stream>>>(accA, N * NF);

    // ---------------- layer 2 ----------------
    init_acc<<<nodeBlocks, 256, 0, stream>>>(accB, b2, N * NF);
    for (int r = 0; r < R; r++) {
        gemm_attn<<<gemmBlocks, 256, 0, stream>>>(
            accA, W2 + (size_t)r * NF * NF, al2 + r * NF, ar2 + r * NF,
            Hbuf, el, er, N);
        aggregate<<<aggBlocks, 256, 0, stream>>>(
            rowptr + r * (N + 1), csr_src + (size_t)r * E, el, er, Hbuf, accB, N);
    }

    head_mean<<<(N * 64 + 255) / 256, 256, 0, stream>>>(accB, (float*)d_out, N);
}

// Round 4
// 1204.401 us; speedup vs baseline: 2.5718x; 1.1274x over previous
//
#include <hip/hip_runtime.h>
#include <hip/hip_bf16.h>
#include <math.h>

#define NF 128          // feature width (both layers): 2 heads x 64
#define HEADS 2
#define HD 64

typedef __attribute__((ext_vector_type(8))) short short8v;   // 8 bf16 = 4 VGPR
typedef __attribute__((ext_vector_type(4))) short short4v;   // 4 bf16 = 2 VGPR
typedef __attribute__((ext_vector_type(4))) float float4v;   // MFMA acc

__device__ inline float leaky02(float v) {
    return v >= 0.0f ? v : 0.2f * v;
}

// fp32 -> bf16 round-to-nearest-even
__device__ inline unsigned short f2bf(float x) {
    unsigned u = __float_as_uint(x);
    u = u + 0x7fffu + ((u >> 16) & 1u);
    return (unsigned short)(u >> 16);
}
__device__ inline float bf2f(unsigned short h) {
    return __uint_as_float(((unsigned)h) << 16);
}

// ---------------------------------------------------------------------------
// Precompute transposed bf16 hi/lo W panels: WT[m][col][k] from W[m][k][col].
// m = layer*3 + relation, 6 matrices of 128x128.
// ---------------------------------------------------------------------------
__global__ __launch_bounds__(256) void convert_w(
    const float* __restrict__ W1, const float* __restrict__ W2,
    unsigned short* __restrict__ WThi, unsigned short* __restrict__ WTlo)
{
    int i = blockIdx.x * 256 + threadIdx.x;
    if (i >= 6 * 16384) return;
    int m = i >> 14, rem = i & 16383;
    int k = rem >> 7, col = rem & 127;
    const float* Wm = (m < 3) ? (W1 + (size_t)m * 16384)
                              : (W2 + (size_t)(m - 3) * 16384);
    float v = Wm[k * 128 + col];
    unsigned short h = f2bf(v);
    unsigned short l = f2bf(v - bf2f(h));
    WThi[(size_t)m * 16384 + col * 128 + k] = h;
    WTlo[(size_t)m * 16384 + col * 128 + k] = l;
}

// ---------------------------------------------------------------------------
// Split-bf16 MFMA GEMM + attention logits.
// H[n][c] = sum_f X[n][f] * W[f][c]  computed as  Xhi*Whi + Xhi*Wlo + Xlo*Whi
// Block: 256 threads = 4 waves; tile 64 rows x 128 cols; K=128 staged in LDS
// once (hi+lo, XOR-swizzled), ONE barrier per block. W read from transposed
// bf16 panels (L2-resident, broadcast). el/er via 16-lane xor-reduce of acc.
// ---------------------------------------------------------------------------
__global__ __launch_bounds__(256) void gemm_attn_mfma(
    const float* __restrict__ X,
    const unsigned short* __restrict__ WThi, const unsigned short* __restrict__ WTlo,
    const float* __restrict__ al, const float* __restrict__ ar,
    float* __restrict__ H, float* __restrict__ el, float* __restrict__ er,
    int n, int do_relu)
{
    __shared__ short Ahi[64 * 128];
    __shared__ short Alo[64 * 128];
    const int t    = threadIdx.x;
    const int row0 = blockIdx.x * 64;

    // ---- stage X tile (64 x 128 fp32) -> bf16 hi/lo in LDS, swizzled
    {
        int row = t >> 2;            // 0..63
        int q   = t & 3;
        int gr  = row0 + row;
        const float* xrow = X + (size_t)gr * NF;
        char* ahB = (char*)Ahi + row * 256;
        char* alB = (char*)Alo + row * 256;
        int sw = (row & 7) << 4;
        bool valid = gr < n;
#pragma unroll
        for (int i = 0; i < 8; i++) {
            int f4 = q + i * 4;                       // float4 index 0..31
            float4 v = make_float4(0.f, 0.f, 0.f, 0.f);
            if (valid) v = *(const float4*)(xrow + f4 * 4);
            if (do_relu) {
                v.x = fmaxf(v.x, 0.f); v.y = fmaxf(v.y, 0.f);
                v.z = fmaxf(v.z, 0.f); v.w = fmaxf(v.w, 0.f);
            }
            unsigned short h0 = f2bf(v.x), h1 = f2bf(v.y),
                           h2 = f2bf(v.z), h3 = f2bf(v.w);
            short4v hh = { (short)h0, (short)h1, (short)h2, (short)h3 };
            short4v ll = { (short)f2bf(v.x - bf2f(h0)),
                           (short)f2bf(v.y - bf2f(h1)),
                           (short)f2bf(v.z - bf2f(h2)),
                           (short)f2bf(v.w - bf2f(h3)) };
            int off = (f4 * 8) ^ sw;                  // byte offset in row
            *(short4v*)(ahB + off) = hh;
            *(short4v*)(alB + off) = ll;
        }
    }
    __syncthreads();

    const int w  = t >> 6;       // wave 0..3 -> rows w*16..w*16+15
    const int l  = t & 63;
    const int lr = l & 15;
    const int lq = l >> 4;

    float4v acc[8];
#pragma unroll
    for (int g = 0; g < 8; g++)
        acc[g] = (float4v){0.f, 0.f, 0.f, 0.f};

    const int rowA = w * 16 + lr;                 // A-frag row (lane&15)
    const char* aBh = (const char*)Ahi + rowA * 256;
    const char* aBl = (const char*)Alo + rowA * 256;
    const int swA = (rowA & 7) << 4;

#pragma unroll
    for (int ks = 0; ks < 4; ks++) {
        int offA = (ks * 64 + lq * 16) ^ swA;
        short8v xh = *(const short8v*)(aBh + offA);
        short8v xl = *(const short8v*)(aBl + offA);
#pragma unroll
        for (int g = 0; g < 8; g++) {
            int bidx = (g * 16 + lr) * 128 + ks * 32 + lq * 8;
            short8v bh = *(const short8v*)(WThi + bidx);
            short8v bl = *(const short8v*)(WTlo + bidx);
            acc[g] = __builtin_amdgcn_mfma_f32_16x16x32_bf16(xh, bh, acc[g], 0, 0, 0);
            acc[g] = __builtin_amdgcn_mfma_f32_16x16x32_bf16(xh, bl, acc[g], 0, 0, 0);
            acc[g] = __builtin_amdgcn_mfma_f32_16x16x32_bf16(xl, bh, acc[g], 0, 0, 0);
        }
    }

    // ---- epilogue: H store + el/er
    // D layout: col = g*16 + lr, row (in 16-strip) = lq*4 + r
    float alv[8], arv[8];
#pragma unroll
    for (int g = 0; g < 8; g++) {
        alv[g] = al[g * 16 + lr];
        arv[g] = ar[g * 16 + lr];
    }

#pragma unroll
    for (int r = 0; r < 4; r++) {
        int gr = row0 + w * 16 + lq * 4 + r;
        if (gr < n) {
            float* hrow = H + (size_t)gr * NF;
#pragma unroll
            for (int g = 0; g < 8; g++)
                hrow[g * 16 + lr] = acc[g][r];
        }
        float e0 = 0.f, e1 = 0.f, f0 = 0.f, f1 = 0.f;
#pragma unroll
        for (int g = 0; g < 4; g++) {
            e0 += acc[g][r] * alv[g];
            f0 += acc[g][r] * arv[g];
        }
#pragma unroll
        for (int g = 4; g < 8; g++) {
            e1 += acc[g][r] * alv[g];
            f1 += acc[g][r] * arv[g];
        }
#pragma unroll
        for (int off = 1; off < 16; off <<= 1) {
            e0 += __shfl_xor(e0, off, 64);
            e1 += __shfl_xor(e1, off, 64);
            f0 += __shfl_xor(f0, off, 64);
            f1 += __shfl_xor(f1, off, 64);
        }
        if (lr == 0 && gr < n) {
            el[gr * 2]     = e0;
            el[gr * 2 + 1] = e1;
            er[gr * 2]     = f0;
            er[gr * 2 + 1] = f1;
        }
    }
}

// ---------------------------------------------------------------------------
// CSR build: histogram -> scan -> place
// ---------------------------------------------------------------------------
__global__ __launch_bounds__(256) void hist_kernel(
    const int* __restrict__ dst, int* __restrict__ deg, int E)
{
    int i = blockIdx.x * 256 + threadIdx.x;
    if (i < E) atomicAdd(&deg[dst[i]], 1);
}

__global__ __launch_bounds__(256) void scan1(
    const int* __restrict__ deg, int* __restrict__ partial,
    int* __restrict__ bsum, int n)
{
    __shared__ int s[256];
    int i = blockIdx.x * 256 + threadIdx.x;
    int t = threadIdx.x;
    int v = (i < n) ? deg[i] : 0;
    s[t] = v;
    __syncthreads();
    for (int off = 1; off < 256; off <<= 1) {
        int x = (t >= off) ? s[t - off] : 0;
        __syncthreads();
        s[t] += x;
        __syncthreads();
    }
    if (i < n) partial[i] = s[t];
    if (t == 255) bsum[blockIdx.x] = s[255];
}

__global__ __launch_bounds__(512) void scan2(int* __restrict__ bsum, int nb)
{
    __shared__ int s[512];
    int t = threadIdx.x;
    int v = (t < nb) ? bsum[t] : 0;
    s[t] = v;
    __syncthreads();
    for (int off = 1; off < 512; off <<= 1) {
        int x = (t >= off) ? s[t - off] : 0;
        __syncthreads();
        s[t] += x;
        __syncthreads();
    }
    if (t < nb) bsum[t] = s[t] - v;   // exclusive
}

__global__ __launch_bounds__(256) void scan3(
    const int* __restrict__ partial, const int* __restrict__ bsum,
    int* __restrict__ rowptr, int n)
{
    int i = blockIdx.x * 256 + threadIdx.x;
    if (i < n) rowptr[i + 1] = partial[i] + bsum[blockIdx.x];
    if (i == 0) rowptr[0] = 0;
}

__global__ __launch_bounds__(256) void place_kernel(
    const int* __restrict__ src, const int* __restrict__ dst,
    const int* __restrict__ rowptr, int* __restrict__ cnt,
    int* __restrict__ csr_src, int E)
{
    int e = blockIdx.x * 256 + threadIdx.x;
    if (e >= E) return;
    int d = dst[e];
    int pos = rowptr[d] + atomicAdd(&cnt[d], 1);
    csr_src[pos] = src[e];
}

// ---------------------------------------------------------------------------
__global__ __launch_bounds__(256) void init_acc(float* __restrict__ acc,
                                                const float* __restrict__ b,
                                                int total)  // N*128, b: [3][128]
{
    int i = blockIdx.x * 256 + threadIdx.x;
    if (i < total) {
        int c = i & 127;
        acc[i] = b[c] + b[128 + c] + b[256 + c];
    }
}

// ---------------------------------------------------------------------------
// Per-destination-node softmax + gather-aggregate. One wave per node.
// ---------------------------------------------------------------------------
__global__ __launch_bounds__(256) void aggregate(
    const int* __restrict__ rowptr, const int* __restrict__ csr_src,
    const float* __restrict__ el, const float* __restrict__ er,
    const float* __restrict__ H, float* __restrict__ acc, int n)
{
    int node = (int)((blockIdx.x * 256 + threadIdx.x) >> 6);
    int lane = threadIdx.x & 63;
    if (node >= n) return;
    int beg = rowptr[node], end = rowptr[node + 1];
    int deg = end - beg;
    if (deg == 0) return;

    const float e0r = er[node * 2];
    const float e1r = er[node * 2 + 1];

    float a0 = 0.0f, a1 = 0.0f;

    if (deg <= 64) {
        int s = 0;
        float v0 = -INFINITY, v1 = -INFINITY;
        if (lane < deg) {
            s = csr_src[beg + lane];
            float2 e = *(const float2*)(el + (size_t)s * 2);
            v0 = leaky02(e.x + e0r);
            v1 = leaky02(e.y + e1r);
        }
        float M0 = v0, M1 = v1;
#pragma unroll
        for (int off = 32; off; off >>= 1) {
            M0 = fmaxf(M0, __shfl_xor(M0, off, 64));
            M1 = fmaxf(M1, __shfl_xor(M1, off, 64));
        }
        float x0 = (lane < deg) ? __expf(v0 - M0) : 0.0f;
        float x1 = (lane < deg) ? __expf(v1 - M1) : 0.0f;
        float S0 = x0, S1 = x1;
#pragma unroll
        for (int off = 32; off; off >>= 1) {
            S0 += __shfl_xor(S0, off, 64);
            S1 += __shfl_xor(S1, off, 64);
        }
        float w0 = x0 / S0;
        float w1 = x1 / S1;

        for (int j = 0; j < deg; j++) {
            int ss    = __shfl(s, j, 64);
            float ww0 = __shfl(w0, j, 64);
            float ww1 = __shfl(w1, j, 64);
            const float* hp = H + (size_t)ss * NF;
            a0 += ww0 * hp[lane];
            a1 += ww1 * hp[64 + lane];
        }
    } else {
        float m0 = -INFINITY, m1 = -INFINITY, d0 = 0.0f, d1 = 0.0f;
        for (int c0 = beg; c0 < end; c0 += 64) {
            int i = c0 + lane;
            float v0 = -INFINITY, v1 = -INFINITY;
            if (i < end) {
                int s = csr_src[i];
                float2 e = *(const float2*)(el + (size_t)s * 2);
                v0 = leaky02(e.x + e0r);
                v1 = leaky02(e.y + e1r);
            }
            float M0 = v0, M1 = v1;
#pragma unroll
            for (int off = 32; off; off >>= 1) {
                M0 = fmaxf(M0, __shfl_xor(M0, off, 64));
                M1 = fmaxf(M1, __shfl_xor(M1, off, 64));
            }
            float x0 = (i < end) ? __expf(v0 - M0) : 0.0f;
            float x1 = (i < end) ? __expf(v1 - M1) : 0.0f;
            float S0 = x0, S1 = x1;
#pragma unroll
            for (int off = 32; off; off >>= 1) {
                S0 += __shfl_xor(S0, off, 64);
                S1 += __shfl_xor(S1, off, 64);
            }
            float nm0 = fmaxf(m0, M0), nm1 = fmaxf(m1, M1);
            d0 = d0 * __expf(m0 - nm0) + S0 * __expf(M0 - nm0);
            d1 = d1 * __expf(m1 - nm1) + S1 * __expf(M1 - nm1);
            m0 = nm0; m1 = nm1;
        }
        float inv0 = 1.0f / d0, inv1 = 1.0f / d1;
        for (int c0 = beg; c0 < end; c0 += 64) {
            int i = c0 + lane;
            int cn = min(64, end - c0);
            int s = 0; float w0 = 0.0f, w1 = 0.0f;
            if (i < end) {
                s = csr_src[i];
                float2 e = *(const float2*)(el + (size_t)s * 2);
                w0 = __expf(leaky02(e.x + e0r) - m0) * inv0;
                w1 = __expf(leaky02(e.y + e1r) - m1) * inv1;
            }
            for (int j = 0; j < cn; j++) {
                int ss    = __shfl(s, j, 64);
                float ww0 = __shfl(w0, j, 64);
                float ww1 = __shfl(w1, j, 64);
                const float* hp = H + (size_t)ss * NF;
                a0 += ww0 * hp[lane];
                a1 += ww1 * hp[64 + lane];
            }
        }
    }
    acc[node * NF + lane]      += a0;
    acc[node * NF + 64 + lane] += a1;
}

// ---------------------------------------------------------------------------
__global__ __launch_bounds__(256) void head_mean(const float* __restrict__ a,
                                                 float* __restrict__ out, int n)
{
    int i = blockIdx.x * 256 + threadIdx.x;
    if (i >= n * 64) return;
    int node = i >> 6, d = i & 63;
    out[i] = 0.5f * (a[node * NF + d] + a[node * NF + 64 + d]);
}

// ---------------------------------------------------------------------------
extern "C" void kernel_launch(void* const* d_in, const int* in_sizes, int n_in,
                              void* d_out, int out_size, void* d_ws, size_t ws_size,
                              hipStream_t stream)
{
    const float* x   = (const float*)d_in[0];
    const int*   src = (const int*)  d_in[1];
    const int*   dst = (const int*)  d_in[2];
    const float* W1  = (const float*)d_in[3];
    const float* al1 = (const float*)d_in[4];
    const float* ar1 = (const float*)d_in[5];
    const float* b1  = (const float*)d_in[6];
    const float* W2  = (const float*)d_in[7];
    const float* al2 = (const float*)d_in[8];
    const float* ar2 = (const float*)d_in[9];
    const float* b2  = (const float*)d_in[10];

    const int N = in_sizes[0] / NF;          // 100000
    const int R = 3;
    const int E = in_sizes[1] / R;           // 800000

    float* ws    = (float*)d_ws;
    float* Hbuf  = ws;                               // N*128
    float* accA  = Hbuf + (size_t)N * NF;            // N*128
    float* accB  = accA + (size_t)N * NF;            // N*128
    float* el    = accB + (size_t)N * NF;            // N*2
    float* er    = el + (size_t)N * 2;               // N*2
    int*   rowptr  = (int*)(er + (size_t)N * 2);     // 3*(N+1)
    int*   csr_src = rowptr + 3 * (N + 1);           // 3*E
    unsigned short* WThi = (unsigned short*)(csr_src + 3 * (size_t)E); // 6*16384
    unsigned short* WTlo = WThi + 6 * 16384;                           // 6*16384
    // CSR-build scratch aliased onto accB (only used before layer 2 init)
    int*   deg     = (int*)accB;                     // N
    int*   partial = deg + N;                        // N
    int*   cnt     = partial + N;                    // N
    int*   bsum    = cnt + N;                        // <=512

    const int nodeBlocks  = (N * NF + 255) / 256;
    const int gemmBlocks  = (N + 63) / 64;
    const int edgeBlocks  = (E + 255) / 256;
    const int aggBlocks   = (N + 3) / 4;             // one wave per node
    const int scanBlocks  = (N + 255) / 256;

    convert_w<<<(6 * 16384 + 255) / 256, 256, 0, stream>>>(W1, W2, WThi, WTlo);

    // ---------------- build CSR for all 3 relations (graph shared by layers)
    for (int r = 0; r < R; r++) {
        const int* dr = dst + (size_t)r * E;
        int* rp = rowptr + r * (N + 1);
        int* cs = csr_src + (size_t)r * E;
        hipMemsetAsync(deg, 0, (size_t)N * 4, stream);
        hipMemsetAsync(cnt, 0, (size_t)N * 4, stream);
        hist_kernel<<<edgeBlocks, 256, 0, stream>>>(dr, deg, E);
        scan1<<<scanBlocks, 256, 0, stream>>>(deg, partial, bsum, N);
        scan2<<<1, 512, 0, stream>>>(bsum, scanBlocks);
        scan3<<<scanBlocks, 256, 0, stream>>>(partial, bsum, rp, N);
        place_kernel<<<edgeBlocks, 256, 0, stream>>>(
            src + (size_t)r * E, dr, rp, cnt, cs, E);
    }

    // ---------------- layer 1 ----------------
    init_acc<<<nodeBlocks, 256, 0, stream>>>(accA, b1, N * NF);
    for (int r = 0; r < R; r++) {
        gemm_attn_mfma<<<gemmBlocks, 256, 0, stream>>>(
            x, WThi + (size_t)r * 16384, WTlo + (size_t)r * 16384,
            al1 + r * NF, ar1 + r * NF, Hbuf, el, er, N, 0);
        aggregate<<<aggBlocks, 256, 0, stream>>>(
            rowptr + r * (N + 1), csr_src + (size_t)r * E, el, er, Hbuf, accA, N);
    }

    // ---------------- layer 2 (ReLU fused into GEMM staging) ----------------
    init_acc<<<nodeBlocks, 256, 0, stream>>>(accB, b2, N * NF);
    for (int r = 0; r < R; r++) {
        gemm_attn_mfma<<<gemmBlocks, 256, 0, stream>>>(
            accA, WThi + (size_t)(3 + r) * 16384, WTlo + (size_t)(3 + r) * 16384,
            al2 + r * NF, ar2 + r * NF, Hbuf, el, er, N, 1);
        aggregate<<<aggBlocks, 256, 0, stream>>>(
            rowptr + r * (N + 1), csr_src + (size_t)r * E, el, er, Hbuf, accB, N);
    }

    head_mean<<<(N * 64 + 255) / 256, 256, 0, stream>>>(accB, (float*)d_out, N);
}